// Round 1
// baseline (1661.585 us; speedup 1.0000x reference)
//
#include <hip/hip_runtime.h>

typedef unsigned short u16;
typedef unsigned int u32;
typedef __attribute__((ext_vector_type(8)))  __bf16 bf16x8;
typedef __attribute__((ext_vector_type(8)))  u16    u16x8;
typedef __attribute__((ext_vector_type(16))) float  f32x16;

#define NPTS 131072
#define DIM  256
#define KC   2048
// derived: 64 centroid tiles of 32; 16 k-steps of 16 dims

__device__ inline u16 bf16_rne(float f) {
    u32 u = __builtin_bit_cast(u32, f);
    u32 r = u + 0x7fffu + ((u >> 16) & 1u);
    return (u16)(r >> 16);
}
__device__ inline float bf16_to_f32(u16 h) {
    u32 u = ((u32)h) << 16;
    return __builtin_bit_cast(float, u);
}

// ---------------------------------------------------------------------------
// Centroid prep: split into bf16 hi/lo in MFMA-A-fragment order + ||c||^2.
// Fragment layout (per 32-row group g): chunk index = ((g*32 + s)*32 + r32)
// where s = kt*2+half selects 8 contiguous dims [kt*16+half*8 .. +7],
// each chunk = 8 bf16 = 16 B. hi array then lo array (offset KC*DIM elems).
// ---------------------------------------------------------------------------
__global__ void cprep_kernel(const float* __restrict__ cen,
                             u16* __restrict__ c_frag,
                             float* __restrict__ c_sq) {
    const int lane = threadIdx.x & 63;
    const int wv   = threadIdx.x >> 6;
    const int n    = blockIdx.x * 4 + wv;              // centroid row
    float4 v = ((const float4*)(cen + (size_t)n * DIM))[lane];  // dims lane*4..+3
    float ss = v.x * v.x + v.y * v.y + v.z * v.z + v.w * v.w;
    float fv[4] = {v.x, v.y, v.z, v.w};
    u16 hh[4], ll[4];
#pragma unroll
    for (int j = 0; j < 4; ++j) {
        hh[j] = bf16_rne(fv[j]);
        ll[j] = bf16_rne(fv[j] - bf16_to_f32(hh[j]));
    }
    const int g = n >> 5, r32 = n & 31;
    const int s = lane >> 1;            // (kt*2+half) for dims lane*4
    const int j0 = (lane & 1) * 4;
    const size_t base = ((size_t)((g * 32 + s) * 32 + r32)) * 8 + j0;
    uint2 h2, l2;
    h2.x = (u32)hh[0] | ((u32)hh[1] << 16); h2.y = (u32)hh[2] | ((u32)hh[3] << 16);
    l2.x = (u32)ll[0] | ((u32)ll[1] << 16); l2.y = (u32)ll[2] | ((u32)ll[3] << 16);
    *(uint2*)(c_frag + base) = h2;
    *(uint2*)(c_frag + (size_t)KC * DIM + base) = l2;
#pragma unroll
    for (int off = 32; off > 0; off >>= 1) ss += __shfl_xor(ss, off);
    if (lane == 0) c_sq[n] = ss;
}

// ---------------------------------------------------------------------------
// Assignment: per wave, 32 points. D[n][m] = sum_k c[n][k]*x[m][k] via
// 3-term split-bf16 MFMA. Lane owns point m = lane&31 (argmin in regs),
// lanes l / l+32 hold complementary centroid rows, merged at the end.
// ---------------------------------------------------------------------------
__global__ __launch_bounds__(256, 2) void assign_kernel(
    const float* __restrict__ x, const u16* __restrict__ c_frag,
    const float* __restrict__ c_sq, int* __restrict__ assigns) {
    __shared__ u16 lds_c[2 * 16384];   // 2 bufs x (hi 16KB + lo 16KB)

    const int tid  = threadIdx.x;
    const int lane = tid & 63;
    const int wv   = tid >> 6;
    const int l31  = lane & 31;
    const int kh   = lane >> 5;        // which half of the 16-dim k-tile

    // ---- load + split this lane's x half-row into 16 hi/lo fragments ----
    const int m = blockIdx.x * 128 + wv * 32 + l31;
    const float4* xr = (const float4*)(x + (size_t)m * DIM);
    bf16x8 xh[16], xl[16];
#pragma unroll
    for (int kt = 0; kt < 16; ++kt) {
        float4 a0 = xr[kt * 4 + kh * 2];
        float4 a1 = xr[kt * 4 + kh * 2 + 1];
        float fv[8] = {a0.x, a0.y, a0.z, a0.w, a1.x, a1.y, a1.z, a1.w};
        u16x8 uh, ul;
#pragma unroll
        for (int j = 0; j < 8; ++j) {
            u16 h = bf16_rne(fv[j]);
            uh[j] = h;
            ul[j] = bf16_rne(fv[j] - bf16_to_f32(h));
        }
        xh[kt] = __builtin_bit_cast(bf16x8, uh);
        xl[kt] = __builtin_bit_cast(bf16x8, ul);
    }

    const float4* csq4 = (const float4*)c_sq;
    float best = 3.4e38f;
    int bidx = 0;

    // prefetch centroid tile 0 (hi 16KB + lo 16KB -> 64B+64B per thread)
    uint4 ph[4], pl[4];
    {
        const uint4* s1 = (const uint4*)(c_frag);
        const uint4* s2 = (const uint4*)(c_frag + (size_t)KC * DIM);
#pragma unroll
        for (int i = 0; i < 4; ++i) { ph[i] = s1[tid + 256 * i]; pl[i] = s2[tid + 256 * i]; }
    }

    int buf = 0;
    for (int nt = 0; nt < 64; ++nt) {
        // commit prefetched tile to LDS[buf]
        uint4* dh = (uint4*)(lds_c + buf * 16384);
        uint4* dl = (uint4*)(lds_c + buf * 16384 + 8192);
#pragma unroll
        for (int i = 0; i < 4; ++i) { dh[tid + 256 * i] = ph[i]; dl[tid + 256 * i] = pl[i]; }
        __syncthreads();
        if (nt < 63) {
            const uint4* s1 = (const uint4*)(c_frag + (size_t)(nt + 1) * 8192);
            const uint4* s2 = (const uint4*)(c_frag + (size_t)KC * DIM + (size_t)(nt + 1) * 8192);
#pragma unroll
            for (int i = 0; i < 4; ++i) { ph[i] = s1[tid + 256 * i]; pl[i] = s2[tid + 256 * i]; }
        }

        f32x16 acc;
#pragma unroll
        for (int r = 0; r < 16; ++r) acc[r] = 0.0f;
        const u16* cb = lds_c + buf * 16384;
#pragma unroll
        for (int kt = 0; kt < 16; ++kt) {
            const int off = ((kt * 2 + kh) * 32 + l31) * 8;
            bf16x8 ch = *(const bf16x8*)(cb + off);
            bf16x8 cl = *(const bf16x8*)(cb + 8192 + off);
            acc = __builtin_amdgcn_mfma_f32_32x32x16_bf16(ch, xh[kt], acc, 0, 0, 0);
            acc = __builtin_amdgcn_mfma_f32_32x32x16_bf16(ch, xl[kt], acc, 0, 0, 0);
            acc = __builtin_amdgcn_mfma_f32_32x32x16_bf16(cl, xh[kt], acc, 0, 0, 0);
        }

        // epilogue: score = 0.5*||c||^2 - dot (monotone equiv of ref formula)
        // D row mapping (verified m74/m101): row = (reg&3) + 8*(reg>>2) + 4*kh
#pragma unroll
        for (int b = 0; b < 4; ++b) {
            float4 cs = csq4[nt * 8 + 2 * b + kh];
            const int n0 = nt * 32 + 8 * b + 4 * kh;
            float v0 = 0.5f * cs.x - acc[b * 4 + 0];
            float v1 = 0.5f * cs.y - acc[b * 4 + 1];
            float v2 = 0.5f * cs.z - acc[b * 4 + 2];
            float v3 = 0.5f * cs.w - acc[b * 4 + 3];
            if (v0 < best) { best = v0; bidx = n0; }
            if (v1 < best) { best = v1; bidx = n0 + 1; }
            if (v2 < best) { best = v2; bidx = n0 + 2; }
            if (v3 < best) { best = v3; bidx = n0 + 3; }
        }
        buf ^= 1;
    }

    // merge the lane pair holding the other 16 centroid rows for point m
    float oval = __shfl_xor(best, 32);
    int   oidx = __shfl_xor(bidx, 32);
    if (oval < best || (oval == best && oidx < bidx)) { best = oval; bidx = oidx; }
    if (lane < 32) assigns[m] = bidx;
}

// ---------------------------------------------------------------------------
// Scatter-add: one thread per (point, 4 dims). Coalesced reads, HW f32 atomics.
// ---------------------------------------------------------------------------
__global__ void scatter_kernel(const float* __restrict__ x,
                               const int* __restrict__ assigns,
                               float* __restrict__ sums,
                               float* __restrict__ counts) {
    const int id = blockIdx.x * 256 + threadIdx.x;   // NPTS*64 items
    const int p = id >> 6, q = id & 63;
    float4 v = ((const float4*)x)[id];
    const int a = assigns[p];
    float* dst = sums + (size_t)a * DIM + q * 4;
    unsafeAtomicAdd(dst + 0, v.x);
    unsafeAtomicAdd(dst + 1, v.y);
    unsafeAtomicAdd(dst + 2, v.z);
    unsafeAtomicAdd(dst + 3, v.w);
    if (q == 0) unsafeAtomicAdd(counts + a, 1.0f);
}

__global__ void finalize_kernel(const float* __restrict__ sums,
                                const float* __restrict__ counts,
                                const float* __restrict__ cen,
                                float* __restrict__ out) {
    const int id = blockIdx.x * 256 + threadIdx.x;   // KC*64 items
    const int k = id >> 6;
    const float cnt = counts[k];
    float4 s = ((const float4*)sums)[id];
    float4 c = ((const float4*)cen)[id];
    float4 o;
    if (cnt > 0.0f) {
        o.x = s.x / cnt; o.y = s.y / cnt; o.z = s.z / cnt; o.w = s.w / cnt;
    } else {
        o = c;
    }
    ((float4*)out)[id] = o;
}

extern "C" void kernel_launch(void* const* d_in, const int* in_sizes, int n_in,
                              void* d_out, int out_size, void* d_ws, size_t ws_size,
                              hipStream_t stream) {
    (void)in_sizes; (void)n_in; (void)out_size; (void)ws_size;
    const float* x   = (const float*)d_in[0];
    const float* cen = (const float*)d_in[1];
    float* out = (float*)d_out;

    char* ws = (char*)d_ws;
    // layout (16B aligned): c_frag 2MB | c_sq 8KB | assigns 512KB | sums 2MB | counts 8KB
    u16*   c_frag  = (u16*)ws;
    float* c_sq    = (float*)(ws + (size_t)2 * KC * DIM * 2);
    int*   assigns = (int*)(ws + (size_t)2 * KC * DIM * 2 + KC * 4);
    float* sums    = (float*)(ws + (size_t)2 * KC * DIM * 2 + KC * 4 + (size_t)NPTS * 4);
    float* counts  = (float*)(ws + (size_t)2 * KC * DIM * 2 + KC * 4 + (size_t)NPTS * 4 +
                              (size_t)KC * DIM * 4);

    hipMemsetAsync(sums, 0, ((size_t)KC * DIM + KC) * sizeof(float), stream);
    cprep_kernel<<<KC / 4, 256, 0, stream>>>(cen, c_frag, c_sq);
    assign_kernel<<<NPTS / 128, 256, 0, stream>>>(x, c_frag, c_sq, assigns);
    scatter_kernel<<<NPTS * 64 / 256, 256, 0, stream>>>(x, assigns, sums, counts);
    finalize_kernel<<<KC * 64 / 256, 256, 0, stream>>>(sums, counts, cen, out);
}

// Round 2
// 1040.769 us; speedup vs baseline: 1.5965x; 1.5965x over previous
//
#include <hip/hip_runtime.h>

typedef unsigned short u16;
typedef unsigned int u32;
typedef __attribute__((ext_vector_type(8)))  __bf16 bf16x8;
typedef __attribute__((ext_vector_type(8)))  u16    u16x8;
typedef __attribute__((ext_vector_type(16))) float  f32x16;

#define NPTS 131072
#define DIM  256
#define KC   2048

__device__ inline u16 bf16_rne(float f) {
    u32 u = __builtin_bit_cast(u32, f);
    u32 r = u + 0x7fffu + ((u >> 16) & 1u);
    return (u16)(r >> 16);
}
__device__ inline float bf16_to_f32(u16 h) {
    u32 u = ((u32)h) << 16;
    return __builtin_bit_cast(float, u);
}

// ---------------------------------------------------------------------------
// Centroid prep: split into bf16 hi/lo in MFMA-A-fragment order + ||c||^2.
// ---------------------------------------------------------------------------
__global__ void cprep_kernel(const float* __restrict__ cen,
                             u16* __restrict__ c_frag,
                             float* __restrict__ c_sq) {
    const int lane = threadIdx.x & 63;
    const int wv   = threadIdx.x >> 6;
    const int n    = blockIdx.x * 4 + wv;              // centroid row
    float4 v = ((const float4*)(cen + (size_t)n * DIM))[lane];  // dims lane*4..+3
    float ss = v.x * v.x + v.y * v.y + v.z * v.z + v.w * v.w;
    float fv[4] = {v.x, v.y, v.z, v.w};
    u16 hh[4], ll[4];
#pragma unroll
    for (int j = 0; j < 4; ++j) {
        hh[j] = bf16_rne(fv[j]);
        ll[j] = bf16_rne(fv[j] - bf16_to_f32(hh[j]));
    }
    const int g = n >> 5, r32 = n & 31;
    const int s = lane >> 1;
    const int j0 = (lane & 1) * 4;
    const size_t base = ((size_t)((g * 32 + s) * 32 + r32)) * 8 + j0;
    uint2 h2, l2;
    h2.x = (u32)hh[0] | ((u32)hh[1] << 16); h2.y = (u32)hh[2] | ((u32)hh[3] << 16);
    l2.x = (u32)ll[0] | ((u32)ll[1] << 16); l2.y = (u32)ll[2] | ((u32)ll[3] << 16);
    *(uint2*)(c_frag + base) = h2;
    *(uint2*)(c_frag + (size_t)KC * DIM + base) = l2;
#pragma unroll
    for (int off = 32; off > 0; off >>= 1) ss += __shfl_xor(ss, off);
    if (lane == 0) c_sq[n] = ss;
}

// ---------------------------------------------------------------------------
// Assignment: per wave, 32 points, 3-term split-bf16 MFMA over all 2048
// centroids, argmin held in registers.
// ---------------------------------------------------------------------------
__global__ __launch_bounds__(256, 2) void assign_kernel(
    const float* __restrict__ x, const u16* __restrict__ c_frag,
    const float* __restrict__ c_sq, int* __restrict__ assigns) {
    __shared__ u16 lds_c[2 * 16384];   // 2 bufs x (hi 16KB + lo 16KB)

    const int tid  = threadIdx.x;
    const int lane = tid & 63;
    const int wv   = tid >> 6;
    const int l31  = lane & 31;
    const int kh   = lane >> 5;

    const int m = blockIdx.x * 128 + wv * 32 + l31;
    const float4* xr = (const float4*)(x + (size_t)m * DIM);
    bf16x8 xh[16], xl[16];
#pragma unroll
    for (int kt = 0; kt < 16; ++kt) {
        float4 a0 = xr[kt * 4 + kh * 2];
        float4 a1 = xr[kt * 4 + kh * 2 + 1];
        float fv[8] = {a0.x, a0.y, a0.z, a0.w, a1.x, a1.y, a1.z, a1.w};
        u16x8 uh, ul;
#pragma unroll
        for (int j = 0; j < 8; ++j) {
            u16 h = bf16_rne(fv[j]);
            uh[j] = h;
            ul[j] = bf16_rne(fv[j] - bf16_to_f32(h));
        }
        xh[kt] = __builtin_bit_cast(bf16x8, uh);
        xl[kt] = __builtin_bit_cast(bf16x8, ul);
    }

    const float4* csq4 = (const float4*)c_sq;
    float best = 3.4e38f;
    int bidx = 0;

    uint4 ph[4], pl[4];
    {
        const uint4* s1 = (const uint4*)(c_frag);
        const uint4* s2 = (const uint4*)(c_frag + (size_t)KC * DIM);
#pragma unroll
        for (int i = 0; i < 4; ++i) { ph[i] = s1[tid + 256 * i]; pl[i] = s2[tid + 256 * i]; }
    }

    int buf = 0;
    for (int nt = 0; nt < 64; ++nt) {
        uint4* dh = (uint4*)(lds_c + buf * 16384);
        uint4* dl = (uint4*)(lds_c + buf * 16384 + 8192);
#pragma unroll
        for (int i = 0; i < 4; ++i) { dh[tid + 256 * i] = ph[i]; dl[tid + 256 * i] = pl[i]; }
        __syncthreads();
        if (nt < 63) {
            const uint4* s1 = (const uint4*)(c_frag + (size_t)(nt + 1) * 8192);
            const uint4* s2 = (const uint4*)(c_frag + (size_t)KC * DIM + (size_t)(nt + 1) * 8192);
#pragma unroll
            for (int i = 0; i < 4; ++i) { ph[i] = s1[tid + 256 * i]; pl[i] = s2[tid + 256 * i]; }
        }

        f32x16 acc;
#pragma unroll
        for (int r = 0; r < 16; ++r) acc[r] = 0.0f;
        const u16* cb = lds_c + buf * 16384;
#pragma unroll
        for (int kt = 0; kt < 16; ++kt) {
            const int off = ((kt * 2 + kh) * 32 + l31) * 8;
            bf16x8 ch = *(const bf16x8*)(cb + off);
            bf16x8 cl = *(const bf16x8*)(cb + 8192 + off);
            acc = __builtin_amdgcn_mfma_f32_32x32x16_bf16(ch, xh[kt], acc, 0, 0, 0);
            acc = __builtin_amdgcn_mfma_f32_32x32x16_bf16(ch, xl[kt], acc, 0, 0, 0);
            acc = __builtin_amdgcn_mfma_f32_32x32x16_bf16(cl, xh[kt], acc, 0, 0, 0);
        }

#pragma unroll
        for (int b = 0; b < 4; ++b) {
            float4 cs = csq4[nt * 8 + 2 * b + kh];
            const int n0 = nt * 32 + 8 * b + 4 * kh;
            float v0 = 0.5f * cs.x - acc[b * 4 + 0];
            float v1 = 0.5f * cs.y - acc[b * 4 + 1];
            float v2 = 0.5f * cs.z - acc[b * 4 + 2];
            float v3 = 0.5f * cs.w - acc[b * 4 + 3];
            if (v0 < best) { best = v0; bidx = n0; }
            if (v1 < best) { best = v1; bidx = n0 + 1; }
            if (v2 < best) { best = v2; bidx = n0 + 2; }
            if (v3 < best) { best = v3; bidx = n0 + 3; }
        }
        buf ^= 1;
    }

    float oval = __shfl_xor(best, 32);
    int   oidx = __shfl_xor(bidx, 32);
    if (oval < best || (oval == best && oidx < bidx)) { best = oval; bidx = oidx; }
    if (lane < 32) assigns[m] = bidx;
}

// ---------------------------------------------------------------------------
// Counting sort replaces the atomic scatter.
// hist: LDS-staged histogram (131k LDS atomics, ~80k global int atomics).
// ---------------------------------------------------------------------------
__global__ void hist_kernel(const int* __restrict__ assigns,
                            int* __restrict__ hist) {
    __shared__ int lh[KC];
    const int tid = threadIdx.x;
#pragma unroll
    for (int i = 0; i < KC / 256; ++i) lh[tid + 256 * i] = 0;
    __syncthreads();
    const int base = blockIdx.x * 2048;          // 64 blocks x 2048 points
#pragma unroll
    for (int j = 0; j < 8; ++j) {
        int a = assigns[base + j * 256 + tid];
        atomicAdd(&lh[a], 1);
    }
    __syncthreads();
#pragma unroll
    for (int i = 0; i < KC / 256; ++i) {
        int v = lh[tid + 256 * i];
        if (v) atomicAdd(&hist[tid + 256 * i], v);
    }
}

// Exclusive prefix sum over KC=2048 counts; one block of 256 threads x 8 each.
__global__ void scan_kernel(const int* __restrict__ hist,
                            int* __restrict__ base_,
                            int* __restrict__ cursor) {
    __shared__ int tmp[256];
    const int tid = threadIdx.x;
    int v[8], s = 0;
#pragma unroll
    for (int j = 0; j < 8; ++j) { v[j] = hist[tid * 8 + j]; s += v[j]; }
    tmp[tid] = s;
    __syncthreads();
    for (int off = 1; off < 256; off <<= 1) {
        int t = (tid >= off) ? tmp[tid - off] : 0;
        __syncthreads();
        tmp[tid] += t;
        __syncthreads();
    }
    int ex = tmp[tid] - s;
#pragma unroll
    for (int j = 0; j < 8; ++j) {
        base_[tid * 8 + j] = ex;
        cursor[tid * 8 + j] = ex;
        ex += v[j];
    }
}

__global__ void reorder_kernel(const int* __restrict__ assigns,
                               int* __restrict__ cursor,
                               int* __restrict__ order) {
    const int p = blockIdx.x * 256 + threadIdx.x;
    const int a = assigns[p];
    int pos = atomicAdd(&cursor[a], 1);
    order[pos] = p;
}

// One block per cluster: 4 waves stride the cluster's rows; float4 lanes.
// order[] index is wave-uniform -> scalar load; row read is a coalesced 1KB burst.
__global__ void reduce_kernel(const float* __restrict__ x,
                              const int* __restrict__ order,
                              const int* __restrict__ base_,
                              const int* __restrict__ hist,
                              float* __restrict__ sums) {
    __shared__ float4 red[256];
    const int tid = threadIdx.x;
    const int g = tid >> 6, l = tid & 63;     // wave id, lane
    const int k = blockIdx.x;
    const int s = base_[k], cnt = hist[k];
    float4 acc = {0.f, 0.f, 0.f, 0.f};
    int i = g;
    for (; i + 8 <= cnt; i += 8) {            // 2-deep per-wave unroll for MLP
        int p0 = order[s + i];
        int p1 = order[s + i + 4];
        float4 v0 = ((const float4*)(x + (size_t)p0 * DIM))[l];
        float4 v1 = ((const float4*)(x + (size_t)p1 * DIM))[l];
        acc.x += v0.x + v1.x; acc.y += v0.y + v1.y;
        acc.z += v0.z + v1.z; acc.w += v0.w + v1.w;
    }
    for (; i < cnt; i += 4) {
        int p = order[s + i];
        float4 v = ((const float4*)(x + (size_t)p * DIM))[l];
        acc.x += v.x; acc.y += v.y; acc.z += v.z; acc.w += v.w;
    }
    red[tid] = acc;
    __syncthreads();
    if (g == 0) {
        float4 a0 = red[l], a1 = red[64 + l], a2 = red[128 + l], a3 = red[192 + l];
        float4 o;
        o.x = a0.x + a1.x + a2.x + a3.x;
        o.y = a0.y + a1.y + a2.y + a3.y;
        o.z = a0.z + a1.z + a2.z + a3.z;
        o.w = a0.w + a1.w + a2.w + a3.w;
        ((float4*)(sums + (size_t)k * DIM))[l] = o;
    }
}

__global__ void finalize_kernel(const float* __restrict__ sums,
                                const int* __restrict__ hist,
                                const float* __restrict__ cen,
                                float* __restrict__ out) {
    const int id = blockIdx.x * 256 + threadIdx.x;   // KC*64 items
    const int k = id >> 6;
    const int cnt = hist[k];
    float4 s = ((const float4*)sums)[id];
    float4 c = ((const float4*)cen)[id];
    float4 o;
    if (cnt > 0) {
        float r = 1.0f / (float)cnt;
        o.x = s.x * r; o.y = s.y * r; o.z = s.z * r; o.w = s.w * r;
    } else {
        o = c;
    }
    ((float4*)out)[id] = o;
}

extern "C" void kernel_launch(void* const* d_in, const int* in_sizes, int n_in,
                              void* d_out, int out_size, void* d_ws, size_t ws_size,
                              hipStream_t stream) {
    (void)in_sizes; (void)n_in; (void)out_size; (void)ws_size;
    const float* x   = (const float*)d_in[0];
    const float* cen = (const float*)d_in[1];
    float* out = (float*)d_out;

    char* ws = (char*)d_ws;
    size_t off = 0;
    u16* c_frag = (u16*)(ws + off);          off += (size_t)2 * KC * DIM * 2;  // 2MB
    float* c_sq = (float*)(ws + off);        off += (size_t)KC * 4;            // 8KB
    int* assigns = (int*)(ws + off);         off += (size_t)NPTS * 4;          // 512KB
    int* hist = (int*)(ws + off);            off += (size_t)KC * 4;            // 8KB
    int* base_ = (int*)(ws + off);           off += (size_t)KC * 4;            // 8KB
    int* cursor = (int*)(ws + off);          off += (size_t)KC * 4;            // 8KB
    int* order = (int*)(ws + off);           off += (size_t)NPTS * 4;          // 512KB
    float* sums = (float*)(ws + off);        off += (size_t)KC * DIM * 4;      // 2MB

    hipMemsetAsync(hist, 0, KC * sizeof(int), stream);
    cprep_kernel<<<KC / 4, 256, 0, stream>>>(cen, c_frag, c_sq);
    assign_kernel<<<NPTS / 128, 256, 0, stream>>>(x, c_frag, c_sq, assigns);
    hist_kernel<<<NPTS / 2048, 256, 0, stream>>>(assigns, hist);
    scan_kernel<<<1, 256, 0, stream>>>(hist, base_, cursor);
    reorder_kernel<<<NPTS / 256, 256, 0, stream>>>(assigns, cursor, order);
    reduce_kernel<<<KC, 256, 0, stream>>>(x, order, base_, hist, sums);
    finalize_kernel<<<KC * 64 / 256, 256, 0, stream>>>(sums, hist, cen, out);
}